// Round 1
// baseline (283.618 us; speedup 1.0000x reference)
//
#include <hip/hip_runtime.h>
#include <hip/hip_bf16.h>

// Problem constants
#define B_    32
#define C_    256     // Cin == Cout
#define H_    56
#define W_    56
#define HP    58      // padded H
#define WPAD  58      // padded W
#define HW    3136    // H_*W_
#define CHW   802816  // C_*H_*W_
#define M_TOT 100352  // B_*H_*W_

typedef char  charx16 __attribute__((ext_vector_type(16)));
typedef int   intx4   __attribute__((ext_vector_type(4)));

#define XPAD_BYTES (B_ * HP * WPAD * C_)        // 27,557,888 (i8)
#define WPK_BYTES  (C_ * 9 * C_)                // 589,824 (i8)

__device__ __forceinline__ int sgn8(float f) {
  return ((f > 0.f) ? 1 : ((f < 0.f) ? -1 : 0)) & 0xff;
}

// ---------------------------------------------------------------------------
// Pack weights: wq[co][s][ci] i8 = sign(w1)+sign(w2) in {-2..2} (= 2*w_ter),
// alphah[co] = 0.5*(mean|w1|+mean|w2|). Coalesced loads via LDS stage.
// ---------------------------------------------------------------------------
__global__ __launch_bounds__(256) void pack_w_kernel(const float* __restrict__ w1,
                                                     const float* __restrict__ w2,
                                                     char* __restrict__ wq,
                                                     float* __restrict__ alphah) {
  __shared__ float l1[2304], l2[2304];
  const int co = blockIdx.x;
  const int tid = threadIdx.x;
  const float* s1 = w1 + co * 2304;
  const float* s2 = w2 + co * 2304;
#pragma unroll
  for (int i = 0; i < 9; ++i) {       // stride-1 across lanes: coalesced
    l1[i * 256 + tid] = s1[i * 256 + tid];
    l2[i * 256 + tid] = s2[i * 256 + tid];
  }
  __syncthreads();
  const int ci = tid;
  float sabs = 0.f;
#pragma unroll
  for (int s = 0; s < 9; ++s) {       // LDS stride 9 (odd) -> bank-spread
    const float a = l1[ci * 9 + s];
    const float b = l2[ci * 9 + s];
    const int sa = (a > 0.f) - (a < 0.f);
    const int sb = (b > 0.f) - (b < 0.f);
    wq[(co * 9 + s) * C_ + ci] = (char)(sa + sb);   // coalesced byte store
    sabs += fabsf(a) + fabsf(b);
  }
#pragma unroll
  for (int off = 32; off > 0; off >>= 1) sabs += __shfl_down(sabs, off, 64);
  __shared__ float red[4];
  if ((tid & 63) == 0) red[tid >> 6] = sabs;
  __syncthreads();
  if (tid == 0)
    alphah[co] = (red[0] + red[1] + red[2] + red[3]) * (0.5f / 2304.0f);
}

// ---------------------------------------------------------------------------
// Pack input: sign(x) NCHW fp32 -> padded NHWC i8 [B][58][58][C].
// One block per (b, padded-y). float4 global reads (16B/lane, coalesced
// 224B segments), pack 4-ci bytes -> b32 LDS writes into [x_pad][ci] tile,
// b128 global stores. Halo zero-filled here (no memset needed).
// ---------------------------------------------------------------------------
#define ROWPC 272
__global__ __launch_bounds__(256) void pack_x_kernel(const float* __restrict__ in,
                                                     char* __restrict__ xp) {
  __shared__ char row[58 * ROWPC];  // 15,776 B
  const int yp = blockIdx.x % HP;
  const int b  = blockIdx.x / HP;
  const int tid = threadIdx.x;

  // zero-fill tile (covers halo + invalid-y rows)
  float4* rz = (float4*)row;
  const float4 z4 = make_float4(0.f, 0.f, 0.f, 0.f);
#pragma unroll
  for (int i = 0; i < 4; ++i) {
    const int idx = i * 256 + tid;
    if (idx < (58 * ROWPC) / 16) rz[idx] = z4;
  }
  __syncthreads();

  const int y = yp - 1;
  const int xq = tid % 14;   // x quad: x = xq*4 .. xq*4+3
  const int cs = tid / 14;   // ci-quad slot 0..18 (252..255 idle)
  if (y >= 0 && y < H_ && cs < 18) {
    const float* base = in + ((size_t)b * C_ * H_ + (size_t)y) * W_ + xq * 4;
#pragma unroll
    for (int k = 0; k < 4; ++k) {
      const int cq = cs + 18 * k;          // ci quad index 0..63
      if (cq < 64) {
        float4 f[4];
#pragma unroll
        for (int j = 0; j < 4; ++j)
          f[j] = *(const float4*)(base + (size_t)(cq * 4 + j) * (H_ * W_));
#pragma unroll
        for (int d = 0; d < 4; ++d) {
          const float v0 = (d == 0) ? f[0].x : (d == 1) ? f[0].y : (d == 2) ? f[0].z : f[0].w;
          const float v1 = (d == 0) ? f[1].x : (d == 1) ? f[1].y : (d == 2) ? f[1].z : f[1].w;
          const float v2 = (d == 0) ? f[2].x : (d == 1) ? f[2].y : (d == 2) ? f[2].z : f[2].w;
          const float v3 = (d == 0) ? f[3].x : (d == 1) ? f[3].y : (d == 2) ? f[3].z : f[3].w;
          const unsigned int pk = (unsigned)sgn8(v0) | ((unsigned)sgn8(v1) << 8) |
                                  ((unsigned)sgn8(v2) << 16) | ((unsigned)sgn8(v3) << 24);
          *(unsigned int*)&row[(xq * 4 + d + 1) * ROWPC + cq * 4] = pk;
        }
      }
    }
  }
  __syncthreads();

  // write padded row: 58 x-slots x 256 B, b128 stores
  const int cc = tid & 15;   // 16 chunks = full 256 B ci-row
  const int xo = tid >> 4;   // 16 x per iter
  char* dst = xp + (size_t)(b * HP + yp) * WPAD * C_;
#pragma unroll
  for (int it = 0; it < 4; ++it) {
    const int xs = it * 16 + xo;
    if (xs < WPAD)
      *(float4*)(dst + xs * C_ + cc * 16) = *(const float4*)&row[xs * ROWPC + cc * 16];
  }
}

// ---------------------------------------------------------------------------
// Implicit-GEMM conv, int8, DEPTH-3 PIPELINE with counted vmcnt (T3/T4):
// 3 LDS buffers, stage(t+2) issued each iter, s_waitcnt vmcnt(6) + raw
// s_barrier per step -- loads always have 2 full compute phases in flight,
// barrier never drains the VMEM queue. Tile 128(co) x 256(m), 512 threads,
// 8 waves in 2x4 grid of 64x64 wave-tiles, mfma_i32_16x16x64_i8.
// LDS 144 KiB -> 1 block/CU (8 waves = 2/SIMD, same as before).
// Same XOR-chunk swizzle (verified 0 bank conflicts) + pre-swizzled
// global_load_lds source. s_setprio(1) around MFMA cluster (T5: pays once
// waves role-split under the counted-vmcnt schedule).
// ---------------------------------------------------------------------------
#define GLL16(src, dst)                                                        \
  __builtin_amdgcn_global_load_lds(                                            \
      (const __attribute__((address_space(1))) void*)(src),                    \
      (__attribute__((address_space(3))) void*)(dst), 16, 0, 0)

__global__ __launch_bounds__(512, 2) void gemm_kernel(const char* __restrict__ xp,
                                                      const char* __restrict__ wq,
                                                      const float* __restrict__ alphah,
                                                      float* __restrict__ out) {
  __shared__ char sA[3 * 128 * 128];  // 48 KiB: [buf][co 128][k 128B]
  __shared__ char sB[3 * 256 * 128];  // 96 KiB: [buf][m 256][k 128B]
  const int tid = threadIdx.x;

  // XCD-paired decode (784 = 98*8, nwg%8==0 -> bijective): blocks id, id+8
  // are the two co-halves of one m-tile -> B-tile L2 reuse on one XCD.
  const int id = blockIdx.x;
  const int xcd = id & 7;
  const int l = id >> 3;
  const int co0 = (l & 1) * 128;
  const int m0 = ((l >> 1) * 8 + xcd) * 256;

  const int srow = tid >> 3;                 // staging row 0..63 (+64*i)
  const int scol = (tid & 7) ^ (srow & 7);   // XOR-swizzled source chunk

  const char* wsrc[2];
  const char* xsrc[4];
#pragma unroll
  for (int i = 0; i < 2; ++i)
    wsrc[i] = wq + (co0 + srow + 64 * i) * 9 * C_ + scol * 16;
#pragma unroll
  for (int i = 0; i < 4; ++i) {
    const int m = m0 + srow + 64 * i;
    const int b = m / HW;
    const int rem = m - b * HW;
    const int y = rem / W_;
    const int x = rem - y * W_;
    xsrc[i] = xp + ((b * HP + y) * WPAD + x) * C_ + scol * 16;
  }

  intx4 acc[4][4] = {};

  const int lane = tid & 63;
  const int wave = tid >> 6;
  const int wm = wave >> 2;   // co 64-half (0..1)
  const int wn = wave & 3;    // m 64-quarter (0..3)
  const int lrow = lane & 15;
  const int quad = lane >> 4;
  const int swk = lrow & 7;
  const int abase = (wm * 64 + lrow) * 128;
  const int bbase = (wn * 64 + lrow) * 128;

  // stage K-step t (s = t>>1 tap, h = t&1 ci-half) into buffer bufi.
  // 6 global_load_lds (16B) per thread: 2 for A (16KB), 4 for B (32KB).
  auto stage = [&](int t, int bufi) {
    const int s = t >> 1;
    const int hh = (t & 1) * 128;
    const int woff = s * C_ + hh;
    const int shoff = ((s / 3) * WPAD + (s % 3)) * C_ + hh;
    char* dA = sA + bufi * 16384 + tid * 16;
    char* dB = sB + bufi * 32768 + tid * 16;
#pragma unroll
    for (int i = 0; i < 2; ++i)
      GLL16(wsrc[i] + woff, dA + i * 8192);
#pragma unroll
    for (int i = 0; i < 4; ++i)
      GLL16(xsrc[i] + shoff, dB + i * 8192);
  };

  stage(0, 0);
  asm volatile("" ::: "memory");  // pin issue order: vmcnt counting relies on it
  stage(1, 1);

  int cb = 0;  // compute buffer = t%3
  int cs = 2;  // stage buffer   = (t+2)%3
  for (int t = 0; t < 18; ++t) {
    // Counted wait: outstanding = stage(t){6} + stage(t+1){6}; vmcnt(6)
    // retires exactly stage(t). lgkmcnt(0): own ds_reads of compute(t-1)
    // retired before other waves' stage writes can land in that buffer.
    if (t < 17)
      asm volatile("s_waitcnt vmcnt(6) lgkmcnt(0)" ::: "memory");
    else
      asm volatile("s_waitcnt vmcnt(0) lgkmcnt(0)" ::: "memory");
    __builtin_amdgcn_s_barrier();   // all waves: buf[t%3] ready, buf[(t-1)%3] free
    if (t < 16) stage(t + 2, cs);   // 2 steps ahead, never drained by barrier

    const char* bA = sA + cb * 16384;
    const char* bB = sB + cb * 32768;
#pragma unroll
    for (int kf = 0; kf < 2; ++kf) {
      const int coff = (((kf << 2) + quad) ^ swk) << 4;  // swizzled chunk
      intx4 af[4], bfv[4];
#pragma unroll
      for (int i = 0; i < 4; ++i)
        af[i] = *(const intx4*)(bA + abase + i * 2048 + coff);
#pragma unroll
      for (int j = 0; j < 4; ++j)
        bfv[j] = *(const intx4*)(bB + bbase + j * 2048 + coff);
      __builtin_amdgcn_s_setprio(1);
#pragma unroll
      for (int i = 0; i < 4; ++i)
#pragma unroll
        for (int j = 0; j < 4; ++j)
          acc[i][j] = __builtin_amdgcn_mfma_i32_16x16x64_i8(af[i], bfv[j],
                                                            acc[i][j], 0, 0, 0);
      __builtin_amdgcn_s_setprio(0);
    }
    cb = (cb == 2) ? 0 : cb + 1;
    cs = (cs == 2) ? 0 : cs + 1;
  }

  // Epilogue: D row (quad*4+r) = co dim, D col (lane&15) = spatial m dim.
  int ob[4];
#pragma unroll
  for (int j = 0; j < 4; ++j) {
    const int m = m0 + wn * 64 + j * 16 + lrow;
    const int b = m / HW;
    const int rem = m - b * HW;
    const int y = rem / W_;
    const int x = rem - y * W_;
    ob[j] = b * CHW + y * W_ + x;
  }
#pragma unroll
  for (int i = 0; i < 4; ++i) {
#pragma unroll
    for (int r = 0; r < 4; ++r) {
      const int co = co0 + wm * 64 + i * 16 + quad * 4 + r;
      const float sc = alphah[co];
#pragma unroll
      for (int j = 0; j < 4; ++j)
        out[ob[j] + co * HW] = (float)acc[i][j][r] * sc;
    }
  }
}

// ---------------------------------------------------------------------------
extern "C" void kernel_launch(void* const* d_in, const int* in_sizes, int n_in,
                              void* d_out, int out_size, void* d_ws, size_t ws_size,
                              hipStream_t stream) {
  const float* input = (const float*)d_in[0];
  const float* w1 = (const float*)d_in[1];
  const float* w2 = (const float*)d_in[2];
  float* out = (float*)d_out;

  char* ws = (char*)d_ws;
  char* xp = ws;                                    // 27,557,888 B
  char* wq = ws + XPAD_BYTES;                       // 589,824 B
  float* alphah = (float*)(ws + XPAD_BYTES + WPK_BYTES);  // 1,024 B

  pack_w_kernel<<<C_, 256, 0, stream>>>(w1, w2, wq, alphah);
  pack_x_kernel<<<B_ * HP, 256, 0, stream>>>(input, xp);
  gemm_kernel<<<(M_TOT / 256) * (C_ / 128), 512, 0, stream>>>(xp, wq, alphah, out);
}

// Round 2
// 265.093 us; speedup vs baseline: 1.0699x; 1.0699x over previous
//
#include <hip/hip_runtime.h>
#include <hip/hip_bf16.h>

// Problem constants
#define B_    32
#define C_    256     // Cin == Cout
#define H_    56
#define W_    56
#define HP    58      // padded H
#define WPAD  58      // padded W
#define HW    3136    // H_*W_
#define CHW   802816  // C_*H_*W_
#define M_TOT 100352  // B_*H_*W_

typedef int intx4 __attribute__((ext_vector_type(4)));

#define XPAD_BYTES (B_ * HP * WPAD * C_)        // 27,557,888 (i8)
#define WPK_BYTES  (C_ * 9 * C_)                // 589,824 (i8)

__device__ __forceinline__ int sgn8(float f) {
  return ((f > 0.f) ? 1 : ((f < 0.f) ? -1 : 0)) & 0xff;
}

// ---------------------------------------------------------------------------
// Pack weights: wq[co][s][ci] i8 = sign(w1)+sign(w2) in {-2..2} (= 2*w_ter),
// alphah[co] = 0.5*(mean|w1|+mean|w2|).
// ---------------------------------------------------------------------------
__global__ __launch_bounds__(256) void pack_w_kernel(const float* __restrict__ w1,
                                                     const float* __restrict__ w2,
                                                     char* __restrict__ wq,
                                                     float* __restrict__ alphah) {
  __shared__ float l1[2304], l2[2304];
  const int co = blockIdx.x;
  const int tid = threadIdx.x;
  const float* s1 = w1 + co * 2304;
  const float* s2 = w2 + co * 2304;
#pragma unroll
  for (int i = 0; i < 9; ++i) {       // stride-1 across lanes: coalesced
    l1[i * 256 + tid] = s1[i * 256 + tid];
    l2[i * 256 + tid] = s2[i * 256 + tid];
  }
  __syncthreads();
  const int ci = tid;
  float sabs = 0.f;
#pragma unroll
  for (int s = 0; s < 9; ++s) {       // LDS stride 9 (odd) -> bank-spread
    const float a = l1[ci * 9 + s];
    const float b = l2[ci * 9 + s];
    const int sa = (a > 0.f) - (a < 0.f);
    const int sb = (b > 0.f) - (b < 0.f);
    wq[(co * 9 + s) * C_ + ci] = (char)(sa + sb);   // coalesced byte store
    sabs += fabsf(a) + fabsf(b);
  }
#pragma unroll
  for (int off = 32; off > 0; off >>= 1) sabs += __shfl_down(sabs, off, 64);
  __shared__ float red[4];
  if ((tid & 63) == 0) red[tid >> 6] = sabs;
  __syncthreads();
  if (tid == 0)
    alphah[co] = (red[0] + red[1] + red[2] + red[3]) * (0.5f / 2304.0f);
}

// ---------------------------------------------------------------------------
// Pack input: sign(x) NCHW fp32 -> padded NHWC i8 [B][58][58][C].
// ---------------------------------------------------------------------------
#define ROWPC 272
__global__ __launch_bounds__(256) void pack_x_kernel(const float* __restrict__ in,
                                                     char* __restrict__ xp) {
  __shared__ char row[58 * ROWPC];  // 15,776 B
  const int yp = blockIdx.x % HP;
  const int b  = blockIdx.x / HP;
  const int tid = threadIdx.x;

  float4* rz = (float4*)row;
  const float4 z4 = make_float4(0.f, 0.f, 0.f, 0.f);
#pragma unroll
  for (int i = 0; i < 4; ++i) {
    const int idx = i * 256 + tid;
    if (idx < (58 * ROWPC) / 16) rz[idx] = z4;
  }
  __syncthreads();

  const int y = yp - 1;
  const int xq = tid % 14;   // x quad: x = xq*4 .. xq*4+3
  const int cs = tid / 14;   // ci-quad slot 0..18 (252..255 idle)
  if (y >= 0 && y < H_ && cs < 18) {
    const float* base = in + ((size_t)b * C_ * H_ + (size_t)y) * W_ + xq * 4;
#pragma unroll
    for (int k = 0; k < 4; ++k) {
      const int cq = cs + 18 * k;          // ci quad index 0..63
      if (cq < 64) {
        float4 f[4];
#pragma unroll
        for (int j = 0; j < 4; ++j)
          f[j] = *(const float4*)(base + (size_t)(cq * 4 + j) * (H_ * W_));
#pragma unroll
        for (int d = 0; d < 4; ++d) {
          const float v0 = (d == 0) ? f[0].x : (d == 1) ? f[0].y : (d == 2) ? f[0].z : f[0].w;
          const float v1 = (d == 0) ? f[1].x : (d == 1) ? f[1].y : (d == 2) ? f[1].z : f[1].w;
          const float v2 = (d == 0) ? f[2].x : (d == 1) ? f[2].y : (d == 2) ? f[2].z : f[2].w;
          const float v3 = (d == 0) ? f[3].x : (d == 1) ? f[3].y : (d == 2) ? f[3].z : f[3].w;
          const unsigned int pk = (unsigned)sgn8(v0) | ((unsigned)sgn8(v1) << 8) |
                                  ((unsigned)sgn8(v2) << 16) | ((unsigned)sgn8(v3) << 24);
          *(unsigned int*)&row[(xq * 4 + d + 1) * ROWPC + cq * 4] = pk;
        }
      }
    }
  }
  __syncthreads();

  const int cc = tid & 15;   // 16 chunks = full 256 B ci-row
  const int xo = tid >> 4;   // 16 x per iter
  char* dst = xp + (size_t)(b * HP + yp) * WPAD * C_;
#pragma unroll
  for (int it = 0; it < 4; ++it) {
    const int xs = it * 16 + xo;
    if (xs < WPAD)
      *(float4*)(dst + xs * C_ + cc * 16) = *(const float4*)&row[xs * ROWPC + cc * 16];
  }
}

// ---------------------------------------------------------------------------
// Implicit-GEMM conv, int8, 8-PHASE SCHEDULE (m201-style port):
// BM=256(co) x BN=256(m), BK=128B, 512 thr / 8 waves (2co x 4m of 128x64).
// LDS [parity][half][128 rows][128B] per matrix (A=64KB, B=64KB).
// Half = quadrant-consumption unit: A-half qm = co rows {qm*64..}+{128+qm*64..},
// B-half qn = m rows {g*64 + qn*32 ..} g=0..3.
// Phase = {ds_read subtile, stage 1 half-tile (2 gll), barrier, lgkmcnt(0),
// 16 MFMA (setprio), barrier}. Quad order (0,0),(0,1),(1,1),(1,0) with
// register reuse: af shared P1-P2 / P3-P4, bv shared P2-P3 (28 b128/K-step).
// vmcnt(4) only at phases 4 & 8 (counted, never drains); stage slots target
// space freed >=1 phase earlier (ledger verified). XOR-chunk LDS swizzle
// (0-conflict verified) via pre-swizzled global source + swizzled ds_read.
// ---------------------------------------------------------------------------
#define GLL16(src, dst)                                                        \
  __builtin_amdgcn_global_load_lds(                                            \
      (const __attribute__((address_space(1))) void*)(src),                    \
      (__attribute__((address_space(3))) void*)(dst), 16, 0, 0)

#define ENDBAR()                                                               \
  do {                                                                         \
    __builtin_amdgcn_s_barrier();                                              \
    asm volatile("" ::: "memory");                                             \
  } while (0)

template <int PAR, int QM>
__device__ __forceinline__ void load_a(const char* sA, int aoff, int c0, int c1,
                                       intx4 (&a0)[4][2]) {
  const char* ab = sA + PAR * 32768 + QM * 16384 + aoff;
#pragma unroll
  for (int ii = 0; ii < 4; ++ii) {
    a0[ii][0] = *(const intx4*)(ab + ii * 2048 + c0);
    a0[ii][1] = *(const intx4*)(ab + ii * 2048 + c1);
  }
}

template <int PAR, int QN>
__device__ __forceinline__ void load_b(const char* sB, int boff, int c0, int c1,
                                       intx4 (&bv)[2][2]) {
  const char* bb = sB + PAR * 32768 + QN * 16384 + boff;
#pragma unroll
  for (int jj = 0; jj < 2; ++jj) {
    bv[jj][0] = *(const intx4*)(bb + jj * 2048 + c0);
    bv[jj][1] = *(const intx4*)(bb + jj * 2048 + c1);
  }
}

template <int QM, int QN>
__device__ __forceinline__ void mfma_quad(intx4 (&a0)[4][2], intx4 (&bv)[2][2],
                                          intx4 (&acc)[8][4]) {
  __builtin_amdgcn_s_barrier();
  asm volatile("s_waitcnt lgkmcnt(0)" ::: "memory");
  __builtin_amdgcn_sched_barrier(0);
  __builtin_amdgcn_s_setprio(1);
#pragma unroll
  for (int ii = 0; ii < 4; ++ii)
#pragma unroll
    for (int jj = 0; jj < 2; ++jj)
#pragma unroll
      for (int kf = 0; kf < 2; ++kf)
        acc[QM * 4 + ii][QN * 2 + jj] = __builtin_amdgcn_mfma_i32_16x16x64_i8(
            a0[ii][kf], bv[jj][kf], acc[QM * 4 + ii][QN * 2 + jj], 0, 0, 0);
  __builtin_amdgcn_s_setprio(0);
}

__global__ __launch_bounds__(512, 2) void gemm_kernel(const char* __restrict__ xp,
                                                      const char* __restrict__ wq,
                                                      const float* __restrict__ alphah,
                                                      float* __restrict__ out) {
  __shared__ char sA[65536];  // [par 2][half 2][row 128][128B]
  __shared__ char sB[65536];
  const int tid = threadIdx.x;

  // m-tile decode, XCD-chunked bijective swizzle: 392 = 8 * 49.
  const int id = blockIdx.x;
  const int m0 = ((id & 7) * 49 + (id >> 3)) * 256;

  // ---- staging bases (pre-swizzled global source, linear LDS dest) ----
  const int rg = tid >> 3;                        // LDS row 0..63 (+64 for g=1)
  const int cgs = ((tid & 7) ^ (rg & 7)) * 16;    // swizzled source chunk

  const char* aw[2][2];   // [half][g]
  const char* xb[2][2];
#pragma unroll
  for (int h = 0; h < 2; ++h) {
#pragma unroll
    for (int g = 0; g < 2; ++g) {
      const int r = rg + g * 64;
      const int co = (g == 0) ? (h * 64 + r) : (128 + h * 64 + (r - 64));
      aw[h][g] = wq + co * 2304 + cgs;
      const int m = m0 + (r >> 5) * 64 + h * 32 + (r & 31);
      const int b = m / HW;
      const int rem = m - b * HW;
      const int y = rem / W_;
      const int x = rem - y * W_;
      xb[h][g] = xp + ((b * HP + y) * WPAD + x) * C_ + cgs;
    }
  }
  char* const dA = sA + tid * 16;   // + par*32768 + h*16384 (+8192 for g=1)
  char* const dB = sB + tid * 16;

  // stage step s, matrix half h (2 x global_load_lds dwordx4 each)
  auto stageA = [&](int s, int h) {
    if (s > 17) return;
    const int tap = s >> 1, ph = s & 1;
    const int off = tap * 256 + ph * 128;
    char* d = dA + ph * 32768 + h * 16384;
    GLL16(aw[h][0] + off, d);
    GLL16(aw[h][1] + off, d + 8192);
  };
  auto stageB = [&](int s, int h) {
    if (s > 17) return;
    const int tap = s >> 1, ph = s & 1;
    const int off = ((tap / 3) * WPAD + (tap % 3)) * C_ + ph * 128;
    char* d = dB + ph * 32768 + h * 16384;
    GLL16(xb[h][0] + off, d);
    GLL16(xb[h][1] + off, d + 8192);
  };

  // ---- read-side lane geometry ----
  const int lane = tid & 63;
  const int wave = tid >> 6;
  const int wm = wave >> 2;       // co 128-half
  const int wn = wave & 3;        // m 64-quarter
  const int lrow = lane & 15;
  const int kq = lane >> 4;       // k 16B-quarter within K=64
  const int c0 = ((kq) ^ (lrow & 7)) * 16;       // kf=0 swizzled chunk
  const int c1 = ((4 + kq) ^ (lrow & 7)) * 16;   // kf=1 swizzled chunk
  const int aoff = wm * 8192 + lrow * 128;       // + ii*2048
  const int boff = wn * 4096 + lrow * 128;       // + jj*2048

  intx4 a0[4][2], bv[2][2];
  intx4 acc[8][4] = {};

  // ---- prologue: step0 fully + step1 Ah0,Bh1; vmcnt(4) retires step0 ----
  stageA(0, 0); stageB(0, 0); stageA(0, 1); stageB(0, 1);
  stageA(1, 0); stageB(1, 1);
  asm volatile("s_waitcnt vmcnt(4)" ::: "memory");
  ENDBAR();

#pragma unroll 1
  for (int i = 0; i < 9; ++i) {
    const int s1 = 2 * i + 1, s2 = 2 * i + 2, s3 = 2 * i + 3;
    // P1 (par0, q00): reads Ah0,Bh0; stages (2i+1).Ah1 (freed prev P7)
    load_a<0, 0>(sA, aoff, c0, c1, a0);
    load_b<0, 0>(sB, boff, c0, c1, bv);
    stageA(s1, 1);
    mfma_quad<0, 0>(a0, bv, acc);
    ENDBAR();
    // P2 (par0, q01): reads Bh1 (af reuse); stages (2i+1).Bh0 (freed prev P8)
    load_b<0, 1>(sB, boff, c0, c1, bv);
    stageB(s1, 0);
    mfma_quad<0, 1>(a0, bv, acc);
    ENDBAR();
    // P3 (par0, q11): reads Ah1 (bv reuse); stages (2i+2).Ah0 (freed P1)
    load_a<0, 1>(sA, aoff, c0, c1, a0);
    stageA(s2, 0);
    mfma_quad<1, 1>(a0, bv, acc);
    ENDBAR();
    // P4 (par0, q10): re-reads Bh0; stages (2i+2).Bh1 (freed P2)
    load_b<0, 0>(sB, boff, c0, c1, bv);
    stageB(s2, 1);
    mfma_quad<1, 0>(a0, bv, acc);
    if (i < 8) asm volatile("s_waitcnt vmcnt(4)" ::: "memory");  // t1 landed
    else       asm volatile("s_waitcnt vmcnt(0)" ::: "memory");
    ENDBAR();
    // P5 (par1, q00): stages (2i+2).Ah1 (freed P3)
    load_a<1, 0>(sA, aoff, c0, c1, a0);
    load_b<1, 0>(sB, boff, c0, c1, bv);
    stageA(s2, 1);
    mfma_quad<0, 0>(a0, bv, acc);
    ENDBAR();
    // P6 (par1, q01): stages (2i+2).Bh0 (freed P4)
    load_b<1, 1>(sB, boff, c0, c1, bv);
    stageB(s2, 0);
    mfma_quad<0, 1>(a0, bv, acc);
    ENDBAR();
    // P7 (par1, q11): stages (2i+3).Ah0 (freed P5)
    load_a<1, 1>(sA, aoff, c0, c1, a0);
    stageA(s3, 0);
    mfma_quad<1, 1>(a0, bv, acc);
    ENDBAR();
    // P8 (par1, q10): stages (2i+3).Bh1 (freed P6)
    load_b<1, 0>(sB, boff, c0, c1, bv);
    stageB(s3, 1);
    mfma_quad<1, 0>(a0, bv, acc);
    if (i < 8) asm volatile("s_waitcnt vmcnt(4)" ::: "memory");  // t2 landed
    else       asm volatile("s_waitcnt vmcnt(0)" ::: "memory");
    ENDBAR();
  }

  // ---- epilogue: D row (kq*4+r) = co, D col (lane&15) = m ----
  int ob[4];
#pragma unroll
  for (int j = 0; j < 4; ++j) {
    const int m = m0 + wn * 64 + j * 16 + lrow;
    const int b = m / HW;
    const int rem = m - b * HW;
    const int y = rem / W_;
    const int x = rem - y * W_;
    ob[j] = b * CHW + y * W_ + x;
  }
#pragma unroll
  for (int ii = 0; ii < 8; ++ii) {
#pragma unroll
    for (int r = 0; r < 4; ++r) {
      const int co = wm * 128 + ii * 16 + kq * 4 + r;
      const float sc = alphah[co];
#pragma unroll
      for (int j = 0; j < 4; ++j)
        out[ob[j] + co * HW] = (float)acc[ii][j][r] * sc;
    }
  }
}

// ---------------------------------------------------------------------------
extern "C" void kernel_launch(void* const* d_in, const int* in_sizes, int n_in,
                              void* d_out, int out_size, void* d_ws, size_t ws_size,
                              hipStream_t stream) {
  const float* input = (const float*)d_in[0];
  const float* w1 = (const float*)d_in[1];
  const float* w2 = (const float*)d_in[2];
  float* out = (float*)d_out;

  char* ws = (char*)d_ws;
  char* xp = ws;                                    // 27,557,888 B
  char* wq = ws + XPAD_BYTES;                       // 589,824 B
  float* alphah = (float*)(ws + XPAD_BYTES + WPK_BYTES);  // 1,024 B

  pack_w_kernel<<<C_, 256, 0, stream>>>(w1, w2, wq, alphah);
  pack_x_kernel<<<B_ * HP, 256, 0, stream>>>(input, xp);
  gemm_kernel<<<392, 512, 0, stream>>>(xp, wq, alphah, out);
}

// Round 3
// 259.626 us; speedup vs baseline: 1.0924x; 1.0211x over previous
//
#include <hip/hip_runtime.h>
#include <hip/hip_bf16.h>

// Problem constants
#define B_    32
#define C_    256     // Cin == Cout
#define H_    56
#define W_    56
#define HP    58      // padded H
#define WPAD  58      // padded W
#define HW    3136    // H_*W_
#define CHW   802816  // C_*H_*W_
#define M_TOT 100352  // B_*H_*W_

typedef int intx4 __attribute__((ext_vector_type(4)));

#define XPAD_BYTES (B_ * HP * WPAD * C_)        // 27,557,888 (i8)
#define WPK_BYTES  (C_ * 9 * C_)                // 589,824 (i8)

__device__ __forceinline__ int sgn8(float f) {
  return ((f > 0.f) ? 1 : ((f < 0.f) ? -1 : 0)) & 0xff;
}

// ---------------------------------------------------------------------------
// Merged pack kernel: blocks [0, B_*HP) run the pack_x role (sign(x) NCHW
// fp32 -> padded NHWC i8), blocks [B_*HP, B_*HP+C_) run the pack_w role
// (wq[co][s][ci] i8 = sign(w1)+sign(w2), alphah[co]). One launch instead of
// two; block-uniform branch, shared LDS union (18448 B).
// ---------------------------------------------------------------------------
#define ROWPC 272
__global__ __launch_bounds__(256) void pack_kernel(const float* __restrict__ in,
                                                   const float* __restrict__ w1,
                                                   const float* __restrict__ w2,
                                                   char* __restrict__ xp,
                                                   char* __restrict__ wq,
                                                   float* __restrict__ alphah) {
  __shared__ char smem[18448];
  const int tid = threadIdx.x;

  if (blockIdx.x < B_ * HP) {
    // ---------------- pack_x role ----------------
    char* row = smem;   // 58 * ROWPC = 15776 B
    const int yp = blockIdx.x % HP;
    const int b  = blockIdx.x / HP;

    float4* rz = (float4*)row;
    const float4 z4 = make_float4(0.f, 0.f, 0.f, 0.f);
#pragma unroll
    for (int i = 0; i < 4; ++i) {
      const int idx = i * 256 + tid;
      if (idx < (58 * ROWPC) / 16) rz[idx] = z4;
    }
    __syncthreads();

    const int y = yp - 1;
    const int xq = tid % 14;   // x quad: x = xq*4 .. xq*4+3
    const int cs = tid / 14;   // ci-quad slot 0..18 (252..255 idle)
    if (y >= 0 && y < H_ && cs < 18) {
      const float* base = in + ((size_t)b * C_ * H_ + (size_t)y) * W_ + xq * 4;
#pragma unroll
      for (int k = 0; k < 4; ++k) {
        const int cq = cs + 18 * k;          // ci quad index 0..63
        if (cq < 64) {
          float4 f[4];
#pragma unroll
          for (int j = 0; j < 4; ++j)
            f[j] = *(const float4*)(base + (size_t)(cq * 4 + j) * (H_ * W_));
#pragma unroll
          for (int d = 0; d < 4; ++d) {
            const float v0 = (d == 0) ? f[0].x : (d == 1) ? f[0].y : (d == 2) ? f[0].z : f[0].w;
            const float v1 = (d == 0) ? f[1].x : (d == 1) ? f[1].y : (d == 2) ? f[1].z : f[1].w;
            const float v2 = (d == 0) ? f[2].x : (d == 1) ? f[2].y : (d == 2) ? f[2].z : f[2].w;
            const float v3 = (d == 0) ? f[3].x : (d == 1) ? f[3].y : (d == 2) ? f[3].z : f[3].w;
            const unsigned int pk = (unsigned)sgn8(v0) | ((unsigned)sgn8(v1) << 8) |
                                    ((unsigned)sgn8(v2) << 16) | ((unsigned)sgn8(v3) << 24);
            *(unsigned int*)&row[(xq * 4 + d + 1) * ROWPC + cq * 4] = pk;
          }
        }
      }
    }
    __syncthreads();

    const int cc = tid & 15;   // 16 chunks = full 256 B ci-row
    const int xo = tid >> 4;   // 16 x per iter
    char* dst = xp + (size_t)(b * HP + yp) * WPAD * C_;
#pragma unroll
    for (int it = 0; it < 4; ++it) {
      const int xs = it * 16 + xo;
      if (xs < WPAD)
        *(float4*)(dst + xs * C_ + cc * 16) = *(const float4*)&row[xs * ROWPC + cc * 16];
    }
  } else {
    // ---------------- pack_w role ----------------
    float* l1 = (float*)smem;          // 2304 f
    float* l2 = l1 + 2304;             // 2304 f
    float* red = (float*)(smem + 18432);  // 4 f
    const int co = blockIdx.x - B_ * HP;
    const float* s1 = w1 + co * 2304;
    const float* s2 = w2 + co * 2304;
#pragma unroll
    for (int i = 0; i < 9; ++i) {       // stride-1 across lanes: coalesced
      l1[i * 256 + tid] = s1[i * 256 + tid];
      l2[i * 256 + tid] = s2[i * 256 + tid];
    }
    __syncthreads();
    const int ci = tid;
    float sabs = 0.f;
#pragma unroll
    for (int s = 0; s < 9; ++s) {       // LDS stride 9 (odd) -> bank-spread
      const float a = l1[ci * 9 + s];
      const float b = l2[ci * 9 + s];
      const int sa = (a > 0.f) - (a < 0.f);
      const int sb = (b > 0.f) - (b < 0.f);
      wq[(co * 9 + s) * C_ + ci] = (char)(sa + sb);   // coalesced byte store
      sabs += fabsf(a) + fabsf(b);
    }
#pragma unroll
    for (int off = 32; off > 0; off >>= 1) sabs += __shfl_down(sabs, off, 64);
    if ((tid & 63) == 0) red[tid >> 6] = sabs;
    __syncthreads();
    if (tid == 0)
      alphah[co] = (red[0] + red[1] + red[2] + red[3]) * (0.5f / 2304.0f);
  }
}

// ---------------------------------------------------------------------------
// Implicit-GEMM conv, int8. Round-0 skeleton (2 blocks/CU, 256 thr/4 waves,
// double-buffered LDS, __syncthreads per K-step, global_load_lds staging)
// with improved geometry: BM=128(co) x BN=256(m) x BK=64. Each wave computes
// the FULL 128co x 64m (8x4 of 16x16 frags): 12 ds_read_b128 feed 32 MFMA
// per K-step (ops/LDS-byte 64 -> 85, LDS traffic/step 96 -> 72 KiB).
// 36 K-steps (9 taps x 4 ci-quarters, K=64B = exactly one mfma-K).
// LDS 48 KB/block -> 2 blocks/CU preserved. Swizzle: 64B rows = 4 chunks,
// chunk ^= (row>>1)&3 -- each (kq, row-octet) lane group covers all 32
// banks exactly once (audited conflict-free; counter verifies).
// ---------------------------------------------------------------------------
#define GLL16(src, dst)                                                        \
  __builtin_amdgcn_global_load_lds(                                            \
      (const __attribute__((address_space(1))) void*)(src),                    \
      (__attribute__((address_space(3))) void*)(dst), 16, 0, 0)

__global__ __launch_bounds__(256, 2) void gemm_kernel(const char* __restrict__ xp,
                                                      const char* __restrict__ wq,
                                                      const float* __restrict__ alphah,
                                                      float* __restrict__ out) {
  __shared__ char sA[2 * 128 * 64];   // 16 KB: [buf][co 128][64B]
  __shared__ char sB[2 * 256 * 64];   // 32 KB: [buf][m 256][64B]
  const int tid = threadIdx.x;

  // XCD-paired decode (784 = 8*98, bijective): blocks id, id+8 are the two
  // co-halves of one 256-wide m-tile -> B-tile L2 reuse within an XCD.
  const int id = blockIdx.x;
  const int xcd = id & 7;
  const int l = id >> 3;              // 0..97
  const int co0 = (l & 1) * 128;
  const int m0 = ((l >> 1) * 8 + xcd) * 256;

  // ---- staging geometry: thread -> (row = tid>>2, chunk = tid&3) ----
  // LDS chunk c_lds holds global chunk c_lds ^ ((row>>1)&3)  (inverse-swz src)
  const int srow = tid >> 2;                        // 0..63
  const int scol = (tid & 3) ^ ((tid >> 3) & 3);    // pre-swizzled src chunk

  const char* wsrc[2];
#pragma unroll
  for (int i = 0; i < 2; ++i)
    wsrc[i] = wq + (co0 + srow + 64 * i) * 2304 + scol * 16;
  const char* xsrc[4];
#pragma unroll
  for (int i = 0; i < 4; ++i) {
    const int m = m0 + srow + 64 * i;
    const int b = m / HW;
    const int rem = m - b * HW;
    const int y = rem / W_;
    const int x = rem - y * W_;
    xsrc[i] = xp + ((b * HP + y) * WPAD + x) * C_ + scol * 16;
  }

  // stage K-step s (tap = s>>2, ci-quarter q = s&3) into buffer (s&1).
  // 6 x global_load_lds dwordx4 per thread: 2 for A (8KB), 4 for B (16KB).
  auto stage = [&](int s) {
    const int tap = s >> 2;
    const int q = s & 3;
    const int woff = tap * 256 + q * 64;
    const int shoff = ((tap / 3) * WPAD + (tap % 3)) * C_ + q * 64;
    char* dA = sA + (s & 1) * 8192 + tid * 16;
    char* dB = sB + (s & 1) * 16384 + tid * 16;
#pragma unroll
    for (int i = 0; i < 2; ++i)
      GLL16(wsrc[i] + woff, dA + i * 4096);
#pragma unroll
    for (int i = 0; i < 4; ++i)
      GLL16(xsrc[i] + shoff, dB + i * 4096);
  };

  // ---- read-side lane geometry ----
  const int lane = tid & 63;
  const int wn = tid >> 6;        // wave = m 64-quarter; all waves span 128 co
  const int lrow = lane & 15;
  const int kq = lane >> 4;       // k 16B-chunk within K=64
  const int coff = (kq ^ ((lrow >> 1) & 3)) * 16;   // swizzled chunk
  const int abase = lrow * 64 + coff;               // + ii*1024
  const int bbase = (wn * 64 + lrow) * 64 + coff;   // + j*1024

  intx4 acc[8][4] = {};

  stage(0);
#pragma unroll 1
  for (int t = 0; t < 36; ++t) {
    __syncthreads();              // drain: buf[t&1] staged, buf[(t+1)&1] free
    if (t < 35) stage(t + 1);     // in flight during compute(t)
    const char* bA = sA + (t & 1) * 8192;
    const char* bB = sB + (t & 1) * 16384;
    intx4 af[8], bv[4];
#pragma unroll
    for (int ii = 0; ii < 8; ++ii)
      af[ii] = *(const intx4*)(bA + abase + ii * 1024);
#pragma unroll
    for (int j = 0; j < 4; ++j)
      bv[j] = *(const intx4*)(bB + bbase + j * 1024);
    __builtin_amdgcn_s_setprio(1);
#pragma unroll
    for (int ii = 0; ii < 8; ++ii)
#pragma unroll
      for (int j = 0; j < 4; ++j)
        acc[ii][j] = __builtin_amdgcn_mfma_i32_16x16x64_i8(af[ii], bv[j],
                                                           acc[ii][j], 0, 0, 0);
    __builtin_amdgcn_s_setprio(0);
  }

  // ---- epilogue: D row (kq*4+r) = co, D col (lane&15) = m ----
  int ob[4];
#pragma unroll
  for (int j = 0; j < 4; ++j) {
    const int m = m0 + wn * 64 + j * 16 + lrow;
    const int b = m / HW;
    const int rem = m - b * HW;
    const int y = rem / W_;
    const int x = rem - y * W_;
    ob[j] = b * CHW + y * W_ + x;
  }
#pragma unroll
  for (int ii = 0; ii < 8; ++ii) {
#pragma unroll
    for (int r = 0; r < 4; ++r) {
      const int co = co0 + ii * 16 + kq * 4 + r;
      const float sc = alphah[co];
#pragma unroll
      for (int j = 0; j < 4; ++j)
        out[ob[j] + co * HW] = (float)acc[ii][j][r] * sc;
    }
  }
}

// ---------------------------------------------------------------------------
extern "C" void kernel_launch(void* const* d_in, const int* in_sizes, int n_in,
                              void* d_out, int out_size, void* d_ws, size_t ws_size,
                              hipStream_t stream) {
  const float* input = (const float*)d_in[0];
  const float* w1 = (const float*)d_in[1];
  const float* w2 = (const float*)d_in[2];
  float* out = (float*)d_out;

  char* ws = (char*)d_ws;
  char* xp = ws;                                    // 27,557,888 B
  char* wq = ws + XPAD_BYTES;                       // 589,824 B
  float* alphah = (float*)(ws + XPAD_BYTES + WPK_BYTES);  // 1,024 B

  pack_kernel<<<B_ * HP + C_, 256, 0, stream>>>(input, w1, w2, xp, wq, alphah);
  gemm_kernel<<<784, 256, 0, stream>>>(xp, wq, alphah, out);
}